// Round 13
// baseline (624.702 us; speedup 1.0000x reference)
//
#include <hip/hip_runtime.h>
#include <hip/hip_bf16.h>

typedef __hip_bfloat16 bf16;
typedef __attribute__((ext_vector_type(8))) short bf16x8_t;
typedef __attribute__((ext_vector_type(8))) unsigned short u16x8;
typedef __attribute__((ext_vector_type(4))) float f32x4_t;
typedef __attribute__((ext_vector_type(2))) float f32x2;

__device__ __forceinline__ float b2f(bf16 v){ return __bfloat162float(v); }
__device__ __forceinline__ bf16 f2b(float v){ return __float2bfloat16(v); }
__device__ __forceinline__ short tobits(float v){ bf16 b = f2b(v); return *(short*)&b; }
__device__ __forceinline__ float us2f(ushort u){ return __uint_as_float(((unsigned)u)<<16); }
__device__ __forceinline__ ushort f2us(float v){ bf16 b = f2b(v); return *(ushort*)&b; }
// exact bf16-pair -> f32x2 (lo = w<<16, hi = w & 0xffff0000)
__device__ __forceinline__ f32x2 bf2x2(unsigned w){
    f32x2 r; r[0] = __uint_as_float(w << 16); r[1] = __uint_as_float(w & 0xffff0000u); return r;
}

#define NN 50000
#define NN128 50048   // NN rounded so GEMM staging needs no M-guard (782*64)
#define NE 250000
#define NEA 500000
#define NR 300
#define EHD 300
#define THD 100
#define RHD 100
#define XP 320      // padded row stride for 300-wide rows (bf16 rows -> 640B, 16B aligned)
#define ERP 320     // padded ER row stride (bf16: 640B rows)
#define RCH 32      // rel-sum chunks per relation
#define NBN 98      // node buckets (512 wide)
#define NBR 75      // rel buckets (4 wide)
#define XCB 7813    // x-cast blocks: ceil(NN*40/256)
#define TRB 60      // transpose tile blocks: 25+25+10 (64x64 tiles)
#define APB 9       // apad blocks: ceil(7*320/256)
#define BCNT_NB 245 // ceil(NEA/2048)
#define NB4 12500   // wave-per-node blocks (4 nodes each)

__device__ __forceinline__ int clampi(int v, int n){ return ((unsigned)v < (unsigned)n) ? v : 0; }

// wave-uniform lane broadcast
__device__ __forceinline__ int rdl_i(int v, int l){ return __builtin_amdgcn_readlane(v, l); }
__device__ __forceinline__ float rdl_f(float v, int l){ return __int_as_float(__builtin_amdgcn_readlane(__float_as_int(v), l)); }

// async global->LDS, 16B per lane (dest = wave-uniform base + lane*16)
typedef const __attribute__((address_space(1))) unsigned int* gas1_t;
typedef __attribute__((address_space(3))) unsigned int* las3_t;
__device__ __forceinline__ void glds16(const void* g, void* l){
    __builtin_amdgcn_global_load_lds((gas1_t)g, (las3_t)l, 16, 0, 0);
}

// ---------- DPP wave reductions ----------
__device__ __forceinline__ float dpp_sum(float x){
    int v;
    v = __builtin_amdgcn_update_dpp(0, __float_as_int(x), 0x111, 0xf, 0xf, true); x += __int_as_float(v);
    v = __builtin_amdgcn_update_dpp(0, __float_as_int(x), 0x112, 0xf, 0xf, true); x += __int_as_float(v);
    v = __builtin_amdgcn_update_dpp(0, __float_as_int(x), 0x114, 0xf, 0xf, true); x += __int_as_float(v);
    v = __builtin_amdgcn_update_dpp(0, __float_as_int(x), 0x118, 0xf, 0xf, true); x += __int_as_float(v);
    v = __builtin_amdgcn_update_dpp(0, __float_as_int(x), 0x142, 0xf, 0xf, true); x += __int_as_float(v);
    v = __builtin_amdgcn_update_dpp(0, __float_as_int(x), 0x143, 0xf, 0xf, true); x += __int_as_float(v);
    return __int_as_float(__builtin_amdgcn_readlane(__float_as_int(x), 63));
}
__device__ __forceinline__ float dpp_max(float x){
    int v;
    v = __builtin_amdgcn_update_dpp(__float_as_int(x), __float_as_int(x), 0x111, 0xf, 0xf, false); x = fmaxf(x, __int_as_float(v));
    v = __builtin_amdgcn_update_dpp(__float_as_int(x), __float_as_int(x), 0x112, 0xf, 0xf, false); x = fmaxf(x, __int_as_float(v));
    v = __builtin_amdgcn_update_dpp(__float_as_int(x), __float_as_int(x), 0x114, 0xf, 0xf, false); x = fmaxf(x, __int_as_float(v));
    v = __builtin_amdgcn_update_dpp(__float_as_int(x), __float_as_int(x), 0x118, 0xf, 0xf, false); x = fmaxf(x, __int_as_float(v));
    v = __builtin_amdgcn_update_dpp(__float_as_int(x), __float_as_int(x), 0x142, 0xf, 0xf, false); x = fmaxf(x, __int_as_float(v));
    v = __builtin_amdgcn_update_dpp(__float_as_int(x), __float_as_int(x), 0x143, 0xf, 0xf, false); x = fmaxf(x, __int_as_float(v));
    return __int_as_float(__builtin_amdgcn_readlane(__float_as_int(x), 63));
}

// ---------- fused prep: x-cast | LDS-tiled weight transposes | apad | bincnt ----------
__global__ __launch_bounds__(256) void k_prepc(const float* __restrict__ xin, ushort* __restrict__ xFu,
                       const float* __restrict__ hw1w, const float* __restrict__ hw2w,
                       const float* __restrict__ tc1w,
                       short* __restrict__ Wt1, short* __restrict__ Wt2, short* __restrict__ Wtc,
                       const float* __restrict__ ahw, const float* __restrict__ atw,
                       const float* __restrict__ ah1w, const float* __restrict__ ajw,
                       const float* __restrict__ aiw, const float* __restrict__ fcw,
                       float* __restrict__ apad, int* __restrict__ bcnt,
                       const int* __restrict__ ji, const int* __restrict__ ht,
                       const int* __restrict__ rel){
    int blk = blockIdx.x, tid = threadIdx.x;
    __shared__ short tld[64][65];
    __shared__ int h[128];
    if(blk < XCB){
        // ---- x cast (padded bf16) ----
        int i = blk*256 + tid;
        if(i < NN*40){
            int nrow = i/40, c8 = i - nrow*40, c = c8*8;
            ushort o[8];
            if(c + 8 <= EHD){
                const float4* src = (const float4*)(xin + (size_t)nrow*EHD + c);
                float4 v0 = src[0], v1 = src[1];
                o[0]=f2us(v0.x); o[1]=f2us(v0.y); o[2]=f2us(v0.z); o[3]=f2us(v0.w);
                o[4]=f2us(v1.x); o[5]=f2us(v1.y); o[6]=f2us(v1.z); o[7]=f2us(v1.w);
            } else {
                #pragma unroll
                for(int k=0;k<8;k++){
                    int cc = c + k;
                    o[k] = (cc < EHD) ? f2us(xin[(size_t)nrow*EHD + cc]) : (ushort)0;
                }
            }
            u16x8 w;
            #pragma unroll
            for(int k=0;k<8;k++) w[k] = o[k];
            *(u16x8*)(xFu + (size_t)nrow*XP + c) = w;
        }
        return;
    }
    if(blk < XCB + TRB){
        // ---- LDS 64x64 tile transpose: coalesced read + coalesced write ----
        int tb = blk - XCB;
        const float* src; short* dst; int SLD, NLIM;
        if(tb < 25){ src = hw1w; dst = Wt1; SLD = EHD; NLIM = EHD; }
        else if(tb < 50){ src = hw2w; dst = Wt2; SLD = EHD; NLIM = EHD; tb -= 25; }
        else { src = tc1w; dst = Wtc; SLD = THD; NLIM = THD; tb -= 50; }
        int tk = tb % 5, tn = tb / 5;
        int k0 = tk*64, n0 = tn*64;
        int c = tid & 63, r0 = tid >> 6;
        #pragma unroll
        for(int i=0;i<16;i++){
            int rr = r0 + i*4;
            int k = k0 + rr, n = n0 + c;
            float v = (k < EHD && n < NLIM) ? src[(size_t)k*SLD + n] : 0.f;
            tld[rr][c] = tobits(v);
        }
        __syncthreads();
        #pragma unroll
        for(int i=0;i<16;i++){
            int nn = r0 + i*4;
            dst[(size_t)(n0 + nn)*320 + (k0 + c)] = tld[c][nn];
        }
        return;
    }
    if(blk < XCB + TRB + APB){
        // ---- apad ----
        int i = (blk - XCB - TRB)*256 + tid;
        if(i < 7*XP){
            int v = i/XP, cc = i - v*XP;
            float val = 0.f;
            if(cc < EHD){
                const float* src = (v==0)?ahw:(v==1)?atw:(v==2)?ah1w:(v==3)?ajw:(v==4)?aiw:
                                   (v==5)? fcw : (fcw + EHD);
                val = src[cc];
            }
            apad[i] = val;
        }
        return;
    }
    // ---- bincnt ----
    int eb = blk - (XCB + TRB + APB);
    int s = eb/BCNT_NB, bx = eb - s*BCNT_NB;
    int n_s = (s == 0) ? NEA : NE;
    int base_e = bx*2048;
    if(base_e >= n_s) return;
    int shift = (s < 3) ? 9 : 2;
    if(tid < 128) h[tid] = 0;
    __syncthreads();
    #pragma unroll
    for(int u=0;u<8;u++){
        int e = base_e + u*256 + tid;
        if(e < n_s){
            int key;
            if(s == 0) key = clampi(ji[NEA + e], NN);
            else if(s == 1) key = clampi(ht[e], NN);
            else if(s == 2) key = clampi(ht[NE + e], NN);
            else key = clampi(rel[e], NR);
            atomicAdd(&h[key >> shift], 1);
        }
    }
    __syncthreads();
    if(tid < 128 && h[tid] > 0) atomicAdd(&bcnt[s*128 + tid], h[tid]);
}

// ---------- segmented scan of bucket counts -> gbase[4][129], gcur[4][128] ----------
__global__ void k_bscan(const int* __restrict__ bcnt, int* __restrict__ gbase, int* __restrict__ gcur){
    __shared__ int lds[512];
    int tid = threadIdx.x;   // 512
    int v = bcnt[tid];
    lds[tid] = v; __syncthreads();
    for(int st=1; st<128; st<<=1){
        int add = ((tid & 127) >= st) ? lds[tid-st] : 0;
        __syncthreads();
        lds[tid] += add;
        __syncthreads();
    }
    int s = tid >> 7, b = tid & 127;
    int excl = lds[tid] - v;
    gbase[s*129 + b] = excl;
    gcur[s*128 + b] = excl;
    if(b == 127) gbase[s*129 + 128] = lds[tid];
}

// ---------- Phase C: LDS-staged binning ----------
__global__ __launch_bounds__(256) void k_bin(const int* __restrict__ ji, const int* __restrict__ ht,
                      const int* __restrict__ rel, int* __restrict__ gcur,
                      int2* __restrict__ t0, int2* __restrict__ t1,
                      int2* __restrict__ t2, int2* __restrict__ t3){
    int s = blockIdx.y;
    int n_s = (s == 0) ? NEA : NE;
    int base_e = blockIdx.x*2048;
    if(base_e >= n_s) return;
    int shift = (s < 3) ? 9 : 2;
    int tid = threadIdx.x;
    __shared__ int cnt[128], lof[128], base[128];
    __shared__ int2 buf[2048];
    if(tid < 128) cnt[tid] = 0;
    __syncthreads();
    int kk[8], pp[8], bb[8], ss[8];
    #pragma unroll
    for(int u=0;u<8;u++){
        int e = base_e + u*256 + tid;
        bb[u] = -1;
        if(e < n_s){
            int key, pay;
            if(s == 0){ key = clampi(ji[NEA + e], NN); pay = clampi(ji[e], NN); }
            else if(s == 1){ key = clampi(ht[e], NN); pay = clampi(rel[e], NR); }
            else if(s == 2){ key = clampi(ht[NE + e], NN); pay = clampi(rel[e], NR); }
            else { key = clampi(rel[e], NR); pay = e; }
            int b = key >> shift;
            kk[u] = key; pp[u] = pay; bb[u] = b;
            ss[u] = atomicAdd(&cnt[b], 1);
        }
    }
    __syncthreads();
    if(tid == 0){
        int run = 0;
        for(int b=0;b<128;b++){ lof[b] = run; run += cnt[b]; }
    }
    __syncthreads();
    #pragma unroll
    for(int u=0;u<8;u++){
        if(bb[u] >= 0){
            int pos = lof[bb[u]] + ss[u];
            buf[pos] = make_int2(kk[u], pp[u]);
        }
    }
    __syncthreads();
    if(tid < 128 && cnt[tid] > 0) base[tid] = atomicAdd(&gcur[s*128 + tid], cnt[tid]);
    __syncthreads();
    int2* tmp = (s==0) ? t0 : (s==1) ? t1 : (s==2) ? t2 : t3;
    int total = lof[127] + cnt[127];
    for(int idx=tid; idx<total; idx+=256){
        int2 kp = buf[idx];
        int b = kp.x >> shift;
        tmp[base[b] + (idx - lof[b])] = kp;
    }
}

// ---------- Phase D: windowed CSR fill ----------
__global__ __launch_bounds__(256) void k_place(const int* __restrict__ gbase,
                        const int2* __restrict__ t0, const int2* __restrict__ t1,
                        const int2* __restrict__ t2, const int2* __restrict__ t3,
                        int* __restrict__ off_all, int* __restrict__ off_h,
                        int* __restrict__ off_t, int* __restrict__ off_r,
                        int* __restrict__ adj_all, int* __restrict__ adj_h,
                        int* __restrict__ adj_t, int* __restrict__ adj_r,
                        float* __restrict__ dinv){
    int s = blockIdx.y, b = blockIdx.x;
    int NB = (s < 3) ? NBN : NBR;
    if(b >= NB) return;
    int W = (s < 3) ? 512 : 4;
    int len = (s < 3) ? NN : NR;
    const int2* tmp = (s==0) ? t0 : (s==1) ? t1 : (s==2) ? t2 : t3;
    int* off = (s==0) ? off_all : (s==1) ? off_h : (s==2) ? off_t : off_r;
    int* adj = (s==0) ? adj_all : (s==1) ? adj_h : (s==2) ? adj_t : adj_r;
    int node0 = b*W;
    int node1 = node0 + W; if(node1 > len) node1 = len;
    int nloc = node1 - node0;
    int wstart = gbase[s*129 + b], wend = gbase[s*129 + b + 1];
    __shared__ int hist[512];
    __shared__ int cur[512];
    __shared__ int sb[256];
    int tid = threadIdx.x;
    for(int k=tid; k<nloc; k+=256) hist[k] = 0;
    __syncthreads();
    for(int idx = wstart + tid; idx < wend; idx += 256){
        int local = tmp[idx].x - node0;
        if((unsigned)local < (unsigned)nloc) atomicAdd(&hist[local], 1);
    }
    __syncthreads();
    int v0 = (2*tid   < nloc) ? hist[2*tid]   : 0;
    int v1 = (2*tid+1 < nloc) ? hist[2*tid+1] : 0;
    int ps = v0 + v1;
    sb[tid] = ps; __syncthreads();
    for(int st=1; st<256; st<<=1){
        int add = (tid >= st) ? sb[tid-st] : 0;
        __syncthreads();
        sb[tid] += add;
        __syncthreads();
    }
    int excl = sb[tid] - ps;
    if(2*tid < nloc){
        int o = wstart + excl;
        off[node0 + 2*tid] = o;
        cur[2*tid] = o;
        if(s == 0) dinv[node0 + 2*tid] = v0 > 0 ? rsqrtf((float)v0) : 0.f;
    }
    if(2*tid+1 < nloc){
        int o = wstart + excl + v0;
        off[node0 + 2*tid+1] = o;
        cur[2*tid+1] = o;
        if(s == 0) dinv[node0 + 2*tid+1] = v1 > 0 ? rsqrtf((float)v1) : 0.f;
    }
    if(b == NB-1 && tid == 0) off[len] = gbase[s*129 + 128];
    __syncthreads();
    for(int idx = wstart + tid; idx < wend; idx += 256){
        int2 kp = tmp[idx];
        int local = kp.x - node0;
        if((unsigned)local < (unsigned)nloc){
            int slot = atomicAdd(&cur[local], 1);
            adj[slot] = kp.y;
        }
    }
}

// ---------- GCN gather: wave per node, 16B row loads, readlane broadcasts ----------
__global__ void k_gcn(const bf16* __restrict__ xs, bf16* __restrict__ xd,
                      const int* __restrict__ off, const int* __restrict__ adjj,
                      const float* __restrict__ dinv){
    int wid = threadIdx.x >> 6, lane = threadIdx.x & 63;
    int n = blockIdx.x*4 + wid;
    if(n >= NN) return;
    float di = dinv[n];
    int s0 = off[n], s1 = off[n+1], cnt = s1 - s0;
    bool act = lane < 40;
    float c0=0,c1=0,c2=0,c3=0,c4=0,c5=0,c6=0,c7=0;
    if(cnt > 0 && cnt <= 64){
        int jl = (lane < cnt) ? clampi(adjj[s0+lane], NN) : 0;
        float dl = (lane < cnt) ? dinv[jl] : 0.f;
        int it = 0;
        for(; it+4 <= cnt; it += 4){
            int j0=rdl_i(jl,it), j1=rdl_i(jl,it+1), j2=rdl_i(jl,it+2), j3=rdl_i(jl,it+3);
            float n0=di*rdl_f(dl,it), n1=di*rdl_f(dl,it+1), n2=di*rdl_f(dl,it+2), n3=di*rdl_f(dl,it+3);
            if(act){
                u16x8 v0 = ((const u16x8*)(xs + (size_t)j0*XP))[lane];
                u16x8 v1 = ((const u16x8*)(xs + (size_t)j1*XP))[lane];
                u16x8 v2 = ((const u16x8*)(xs + (size_t)j2*XP))[lane];
                u16x8 v3 = ((const u16x8*)(xs + (size_t)j3*XP))[lane];
                c0 += n0*us2f(v0[0])+n1*us2f(v1[0])+n2*us2f(v2[0])+n3*us2f(v3[0]);
                c1 += n0*us2f(v0[1])+n1*us2f(v1[1])+n2*us2f(v2[1])+n3*us2f(v3[1]);
                c2 += n0*us2f(v0[2])+n1*us2f(v1[2])+n2*us2f(v2[2])+n3*us2f(v3[2]);
                c3 += n0*us2f(v0[3])+n1*us2f(v1[3])+n2*us2f(v2[3])+n3*us2f(v3[3]);
                c4 += n0*us2f(v0[4])+n1*us2f(v1[4])+n2*us2f(v2[4])+n3*us2f(v3[4]);
                c5 += n0*us2f(v0[5])+n1*us2f(v1[5])+n2*us2f(v2[5])+n3*us2f(v3[5]);
                c6 += n0*us2f(v0[6])+n1*us2f(v1[6])+n2*us2f(v2[6])+n3*us2f(v3[6]);
                c7 += n0*us2f(v0[7])+n1*us2f(v1[7])+n2*us2f(v2[7])+n3*us2f(v3[7]);
            }
        }
        for(; it < cnt; it++){
            int j0 = rdl_i(jl, it);
            float n0 = di*rdl_f(dl, it);
            if(act){
                u16x8 v0 = ((const u16x8*)(xs + (size_t)j0*XP))[lane];
                c0 += n0*us2f(v0[0]); c1 += n0*us2f(v0[1]); c2 += n0*us2f(v0[2]); c3 += n0*us2f(v0[3]);
                c4 += n0*us2f(v0[4]); c5 += n0*us2f(v0[5]); c6 += n0*us2f(v0[6]); c7 += n0*us2f(v0[7]);
            }
        }
    } else if(cnt > 64){
        for(int it=s0; it<s1; it++){
            int j = clampi(adjj[it], NN);
            float nr = di * dinv[j];
            if(act){
                u16x8 v0 = ((const u16x8*)(xs + (size_t)j*XP))[lane];
                c0 += nr*us2f(v0[0]); c1 += nr*us2f(v0[1]); c2 += nr*us2f(v0[2]); c3 += nr*us2f(v0[3]);
                c4 += nr*us2f(v0[4]); c5 += nr*us2f(v0[5]); c6 += nr*us2f(v0[6]); c7 += nr*us2f(v0[7]);
            }
        }
    }
    if(act){
        u16x8 w;
        w[0]=f2us(fmaxf(c0,0.f)); w[1]=f2us(fmaxf(c1,0.f)); w[2]=f2us(fmaxf(c2,0.f)); w[3]=f2us(fmaxf(c3,0.f));
        w[4]=f2us(fmaxf(c4,0.f)); w[5]=f2us(fmaxf(c5,0.f)); w[6]=f2us(fmaxf(c6,0.f)); w[7]=f2us(fmaxf(c7,0.f));
        ((u16x8*)(xd + (size_t)n*XP))[lane] = w;
    }
}

// ---------- MFMA GEMM: 64x64 tile, glds staging + XOR swizzle, 1D grid with
// bijective XCD-chunk swizzle + column-fastest panel decode for A-panel L2 reuse ----------
template<int MODE>
__global__ __launch_bounds__(256) void k_gemm_mfma(const bf16* __restrict__ X,
                       const short* __restrict__ Wt, const float* __restrict__ bias,
                       bf16* __restrict__ out, const bf16* __restrict__ Xprev,
                       int M, int K, int Ncols, int ldOut, int ncb){
    __shared__ short As[64*32];
    __shared__ short Bs[64*32];
    int tid = threadIdx.x;
    int bid = blockIdx.x;
    int nwg = gridDim.x;
    int xcd = bid & 7, idx = bid >> 3;
    int q = nwg >> 3, rr = nwg & 7;
    int logical = (xcd < rr ? xcd*(q+1) : rr*(q+1) + (xcd-rr)*q) + idx;
    int pan = logical / ncb;
    int bm = pan*64, bn = (logical - pan*ncb)*64;
    int wid = tid>>6, lane = tid&63;
    int wm = (wid&1)*32, wn = (wid>>1)*32;
    int lm = lane&15, lq = lane>>4;
    f32x4_t acc00={0,0,0,0}, acc01={0,0,0,0}, acc10={0,0,0,0}, acc11={0,0,0,0};
    int srow = tid>>2, ssl = tid&3;
    int ssl_sw = ssl ^ ((srow>>1)&3);
    short* ldsA = As + (size_t)(wid*64)*8;
    short* ldsB = Bs + (size_t)(wid*64)*8;
    const bf16*  gA = X  + (size_t)(bm + srow)*K + ssl_sw*8;
    const short* gB = Wt + (size_t)(bn + srow)*K + ssl_sw*8;
    for(int k0=0; k0<K; k0+=32){
        glds16(gA + k0, ldsA);
        glds16(gB + k0, ldsB);
        __syncthreads();
        int ra0 = wm + lm, ra1 = wm + 16 + lm;
        int rb0 = wn + lm, rb1 = wn + 16 + lm;
        bf16x8_t a0 = *(const bf16x8_t*)(As + ra0*32 + ((lq ^ ((ra0>>1)&3))*8));
        bf16x8_t a1 = *(const bf16x8_t*)(As + ra1*32 + ((lq ^ ((ra1>>1)&3))*8));
        bf16x8_t b0 = *(const bf16x8_t*)(Bs + rb0*32 + ((lq ^ ((rb0>>1)&3))*8));
        bf16x8_t b1 = *(const bf16x8_t*)(Bs + rb1*32 + ((lq ^ ((rb1>>1)&3))*8));
        acc00 = __builtin_amdgcn_mfma_f32_16x16x32_bf16(a0, b0, acc00, 0, 0, 0);
        acc01 = __builtin_amdgcn_mfma_f32_16x16x32_bf16(a0, b1, acc01, 0, 0, 0);
        acc10 = __builtin_amdgcn_mfma_f32_16x16x32_bf16(a1, b0, acc10, 0, 0, 0);
        acc11 = __builtin_amdgcn_mfma_f32_16x16x32_bf16(a1, b1, acc11, 0, 0, 0);
        __syncthreads();
    }
    #pragma unroll
    for(int tm=0;tm<2;tm++){
        #pragma unroll
        for(int tn=0;tn<2;tn++){
            f32x4_t a = tm==0 ? (tn==0 ? acc00 : acc01) : (tn==0 ? acc10 : acc11);
            int gn = bn + wn + tn*16 + lm;
            if(gn >= Ncols) continue;
            float bi = bias[gn];
            #pragma unroll
            for(int r2=0;r2<4;r2++){
                int gm = bm + wm + tm*16 + lq*4 + r2;
                if(gm >= M) continue;
                float t = a[r2] + bi;
                size_t p = (size_t)gm*ldOut + gn;
                if(MODE == 0){
                    out[p] = f2b(t);
                } else {
                    float g = __builtin_amdgcn_rcpf(1.f + __expf(-t));
                    out[p] = f2b(g*b2f(out[p]) + (1.f - g)*b2f(Xprev[p]));
                }
            }
        }
    }
}

// ---------- per-relation sums; head/tail split across 256 threads (1 load/edge/thread) ----------
__global__ __launch_bounds__(256) void k_relsum2(const bf16* __restrict__ s, const int* __restrict__ ht,
                          const int* __restrict__ off_r, const int* __restrict__ adj_r,
                          float* __restrict__ RFpart){
    int r = blockIdx.x, c = blockIdx.y;
    int tid = threadIdx.x;
    bool isHead = tid < THD;
    bool isTail = (tid >= 128 && tid < 128 + THD);
    if(!isHead && !isTail) return;
    int d = isHead ? tid : tid - 128;
    int hoff = isHead ? 0 : NE;
    int slot = isHead ? 0 : THD;
    int s0 = off_r[r], s1 = off_r[r+1];
    int cnt = s1 - s0;
    float acc = 0.f;
    if(cnt > 0){
        int per = (cnt + RCH - 1)/RCH;
        int lo = s0 + c*per, hi = lo + per; if(hi > s1) hi = s1;
        for(int it=lo; it<hi; it++){
            int e = clampi(adj_r[it], NE);
            int node = clampi(ht[hoff + e], NN);
            acc += b2f(s[(size_t)node*THD + d]);
        }
    }
    RFpart[(size_t)(r*RCH + c)*2*THD + slot + d] = acc;
}

// ---------- fused: slab-reduce -> means + x_res2 (in LDS) -> ER (bf16) + cvec ----------
__global__ void k_reler(const float* __restrict__ RFpart, const int* __restrict__ off_r,
                        const float* __restrict__ sr1w, const float* __restrict__ sr1b,
                        const float* w0, const float* b0, const float* w1, const float* b1,
                        const float* w2, const float* b2,
                        const float* ar1, const float* ar2, const float* ar3,
                        bf16* __restrict__ ER, float* __restrict__ cvec){
    int r = blockIdx.x, kk = blockIdx.y;
    const float* w = kk==0 ? w0 : (kk==1 ? w1 : w2);
    const float* b = kk==0 ? b0 : (kk==1 ? b1 : b2);
    const float* a = kk==0 ? ar1 : (kk==1 ? ar2 : ar3);
    int tid = threadIdx.x;
    __shared__ float rfs[EHD];
    int cnt = off_r[r+1] - off_r[r];
    float inv = 1.f/(float)(cnt > 1 ? cnt : 1);
    for(int d=tid; d<2*THD; d+=256){
        float sacc = 0.f;
        #pragma unroll
        for(int c=0;c<RCH;c++) sacc += RFpart[(size_t)(r*RCH + c)*2*THD + d];
        rfs[THD + d] = sacc*inv;
    }
    __syncthreads();
    if(tid < RHD){
        float v = 0.f;
        if(cnt > 0){
            v = sr1b[tid];
            for(int k2=0; k2<2*THD; k2++) v += rfs[THD + k2] * sr1w[k2*RHD + tid];
        }
        rfs[tid] = v;
    }
    __syncthreads();
    float pd = 0.f;
    for(int o = tid; o < ERP; o += 256){
        float v = 0.f;
        if(o < EHD){
            v = b[o];
            for(int d=0; d<EHD; d++) v += rfs[d] * w[(size_t)d*EHD + o];
            pd += v * a[o];
        }
        ER[((size_t)kk*NR + r)*ERP + o] = f2b(v);
    }
    __shared__ float red[4];
    pd = dpp_sum(pd);
    if((tid & 63) == 0) red[tid>>6] = pd;
    __syncthreads();
    if(tid == 0) cvec[kk*NR + r] = red[0]+red[1]+red[2]+red[3];
}

// ---------- one r2e round; bf16 ER gather, packed f32x2 accumulation ----------
__device__ __forceinline__ void r2e_round(float* xv, bool act, int lane, int s0, int s1,
        int rl, float cval,
        const int* __restrict__ adjrel, const bf16* __restrict__ ERk,
        const float* __restrict__ ck, const float* __restrict__ an){
    float p = 0.f;
    if(act){
        const float4* a4 = (const float4*)an;
        float4 a0 = a4[2*lane], a1 = a4[2*lane+1];
        p = xv[0]*a0.x + xv[1]*a0.y + xv[2]*a0.z + xv[3]*a0.w
          + xv[4]*a1.x + xv[5]*a1.y + xv[6]*a1.z + xv[7]*a1.w;
    }
    p = dpp_sum(p);
    int cnt = s1 - s0;
    if(cnt <= 0) return;
    f32x2 a01={0,0}, a23={0,0}, a45={0,0}, a67={0,0};
    if(cnt <= 64){
        float lg = p + cval;
        lg = lg > 0 ? lg : 0.01f*lg;
        float mx = dpp_max((lane < cnt) ? lg : -1e30f);
        float ex = (lane < cnt) ? __expf(lg - mx) : 0.f;
        float al = ex * __builtin_amdgcn_rcpf(dpp_sum(ex));
        int it = 0;
        for(; it+4 <= cnt; it += 4){
            int r0i = rdl_i(rl, it),   r1i = rdl_i(rl, it+1);
            int r2i = rdl_i(rl, it+2), r3i = rdl_i(rl, it+3);
            float q0 = rdl_f(al, it),   q1 = rdl_f(al, it+1);
            float q2 = rdl_f(al, it+2), q3 = rdl_f(al, it+3);
            if(act){
                uint4 e0 = ((const uint4*)(ERk + (size_t)r0i*ERP))[lane];
                uint4 e1 = ((const uint4*)(ERk + (size_t)r1i*ERP))[lane];
                uint4 e2 = ((const uint4*)(ERk + (size_t)r2i*ERP))[lane];
                uint4 e3 = ((const uint4*)(ERk + (size_t)r3i*ERP))[lane];
                a01 += q0*bf2x2(e0.x) + q1*bf2x2(e1.x) + q2*bf2x2(e2.x) + q3*bf2x2(e3.x);
                a23 += q0*bf2x2(e0.y) + q1*bf2x2(e1.y) + q2*bf2x2(e2.y) + q3*bf2x2(e3.y);
                a45 += q0*bf2x2(e0.z) + q1*bf2x2(e1.z) + q2*bf2x2(e2.z) + q3*bf2x2(e3.z);
                a67 += q0*bf2x2(e0.w) + q1*bf2x2(e1.w) + q2*bf2x2(e2.w) + q3*bf2x2(e3.w);
            }
        }
        for(; it < cnt; it++){
            int r0i = rdl_i(rl, it);
            float q0 = rdl_f(al, it);
            if(act){
                uint4 e0 = ((const uint4*)(ERk + (size_t)r0i*ERP))[lane];
                a01 += q0*bf2x2(e0.x); a23 += q0*bf2x2(e0.y);
                a45 += q0*bf2x2(e0.z); a67 += q0*bf2x2(e0.w);
            }
        }
    } else {
        float mx = -1e30f;
        for(int it=s0; it<s1; it++){
            float lg = p + ck[clampi(adjrel[it], NR)];
            lg = lg > 0 ? lg : 0.01f*lg;
            mx = fmaxf(mx, lg);
        }
        float ssum = 0.f;
        for(int it=s0; it<s1; it++){
            float lg = p + ck[clampi(adjrel[it], NR)];
            lg = lg > 0 ? lg : 0.01f*lg;
            ssum += __expf(lg - mx);
        }
        float rinv = __builtin_amdgcn_rcpf(ssum);
        for(int it=s0; it<s1; it++){
            int r = clampi(adjrel[it], NR);
            float lg = p + ck[r];
            lg = lg > 0 ? lg : 0.01f*lg;
            float aw = __expf(lg - mx)*rinv;
            if(act){
                uint4 e0 = ((const uint4*)(ERk + (size_t)r*ERP))[lane];
                a01 += aw*bf2x2(e0.x); a23 += aw*bf2x2(e0.y);
                a45 += aw*bf2x2(e0.z); a67 += aw*bf2x2(e0.w);
            }
        }
    }
    xv[0] += fmaxf(a01[0],0.f); xv[1] += fmaxf(a01[1],0.f);
    xv[2] += fmaxf(a23[0],0.f); xv[3] += fmaxf(a23[1],0.f);
    xv[4] += fmaxf(a45[0],0.f); xv[5] += fmaxf(a45[1],0.f);
    xv[6] += fmaxf(a67[0],0.f); xv[7] += fmaxf(a67[1],0.f);
}

// ---------- fused: three r2e rounds + ajv ----------
__global__ void k_r2e3(bf16* __restrict__ x,
                       const int* __restrict__ off_h, const int* __restrict__ adj_h,
                       const int* __restrict__ off_t, const int* __restrict__ adj_t,
                       const bf16* __restrict__ ER, const float* __restrict__ cvec,
                       const float* __restrict__ apad, float* __restrict__ ajv){
    int wid = threadIdx.x >> 6, lane = threadIdx.x & 63;
    int n = blockIdx.x*4 + wid;
    if(n >= NN) return;
    bool act = lane < 40;
    u16x8* xr = (u16x8*)(x + (size_t)n*XP);
    float xv[8];
    if(act){
        u16x8 v = xr[lane];
        #pragma unroll
        for(int k=0;k<8;k++) xv[k] = us2f(v[k]);
    } else {
        #pragma unroll
        for(int k=0;k<8;k++) xv[k] = 0.f;
    }
    int h0 = off_h[n], h1 = off_h[n+1];
    int t0_ = off_t[n], t1_ = off_t[n+1];
    int hcnt = h1 - h0, tcnt = t1_ - t0_;
    int rlh = (hcnt > 0 && hcnt <= 64 && lane < hcnt) ? clampi(adj_h[h0+lane], NR) : 0;
    int rlt = (tcnt > 0 && tcnt <= 64 && lane < tcnt) ? clampi(adj_t[t0_+lane], NR) : 0;
    float ch1 = cvec[rlh], ctv = cvec[NR + rlt], ch3 = cvec[2*NR + rlh];
    r2e_round(xv, act, lane, h0, h1, rlh, ch1, adj_h, ER,                    cvec,      apad);
    r2e_round(xv, act, lane, t0_, t1_, rlt, ctv, adj_t, ER + (size_t)NR*ERP, cvec+NR,   apad + XP);
    r2e_round(xv, act, lane, h0, h1, rlh, ch3, adj_h, ER + (size_t)2*NR*ERP, cvec+2*NR, apad + 2*XP);
    {
        float p = 0.f;
        if(act){
            const float4* a4 = (const float4*)(apad + 3*XP);
            float4 a0 = a4[2*lane], a1 = a4[2*lane+1];
            p = xv[0]*a0.x + xv[1]*a0.y + xv[2]*a0.z + xv[3]*a0.w
              + xv[4]*a1.x + xv[5]*a1.y + xv[6]*a1.z + xv[7]*a1.w;
        }
        p = dpp_sum(p);
        if(lane == 0) ajv[n] = p;
    }
    if(act){
        u16x8 w;
        #pragma unroll
        for(int k=0;k<8;k++) w[k] = f2us(xv[k]);
        xr[lane] = w;
    }
}

// ---------- final GAT + fc; 4-edge gather ----------
__global__ void k_final(const bf16* __restrict__ x, const float* __restrict__ ajv,
                        const int* __restrict__ off, const int* __restrict__ adjj,
                        const float* __restrict__ apad, const float* __restrict__ fcb,
                        float* __restrict__ out){
    int wid = threadIdx.x >> 6, lane = threadIdx.x & 63;
    int n = blockIdx.x*4 + wid;
    if(n >= NN) return;
    bool act = lane < 40;
    float xv[8];
    if(act){
        u16x8 v = ((const u16x8*)(x + (size_t)n*XP))[lane];
        #pragma unroll
        for(int k=0;k<8;k++) xv[k] = us2f(v[k]);
    } else {
        #pragma unroll
        for(int k=0;k<8;k++) xv[k] = 0.f;
    }
    float p = 0.f;
    if(act){
        const float4* a4 = (const float4*)(apad + 4*XP);
        float4 a0 = a4[2*lane], a1 = a4[2*lane+1];
        p = xv[0]*a0.x + xv[1]*a0.y + xv[2]*a0.z + xv[3]*a0.w
          + xv[4]*a1.x + xv[5]*a1.y + xv[6]*a1.z + xv[7]*a1.w;
    }
    p = dpp_sum(p);
    int s0 = off[n], s1 = off[n+1], cnt = s1 - s0;
    float c0=0,c1=0,c2=0,c3=0,c4=0,c5=0,c6=0,c7=0;
    if(cnt > 0 && cnt <= 64){
        int jl = (lane < cnt) ? clampi(adjj[s0+lane], NN) : 0;
        float av = (lane < cnt) ? ajv[jl] : 0.f;
        float lg = p + av;
        lg = lg > 0 ? lg : 0.01f*lg;
        float mx = dpp_max((lane < cnt) ? lg : -1e30f);
        float ex = (lane < cnt) ? __expf(lg - mx) : 0.f;
        float al = ex * __builtin_amdgcn_rcpf(dpp_sum(ex));
        int it = 0;
        for(; it+4 <= cnt; it += 4){
            int j0=rdl_i(jl,it), j1=rdl_i(jl,it+1), j2=rdl_i(jl,it+2), j3=rdl_i(jl,it+3);
            float q0=rdl_f(al,it), q1=rdl_f(al,it+1), q2=rdl_f(al,it+2), q3=rdl_f(al,it+3);
            if(act){
                u16x8 v0 = ((const u16x8*)(x + (size_t)j0*XP))[lane];
                u16x8 v1 = ((const u16x8*)(x + (size_t)j1*XP))[lane];
                u16x8 v2 = ((const u16x8*)(x + (size_t)j2*XP))[lane];
                u16x8 v3 = ((const u16x8*)(x + (size_t)j3*XP))[lane];
                c0 += q0*us2f(v0[0])+q1*us2f(v1[0])+q2*us2f(v2[0])+q3*us2f(v3[0]);
                c1 += q0*us2f(v0[1])+q1*us2f(v1[1])+q2*us2f(v2[1])+q3*us2f(v3[1]);
                c2 += q0*us2f(v0[2])+q1*us2f(v1[2])+q2*us2f(v2[2])+q3*us2f(v3[2]);
                c3 += q0*us2f(v0[3])+q1*us2f(v1[3])+q2*us2f(v2[3])+q3*us2f(v3[3]);
                c4 += q0*us2f(v0[4])+q1*us2f(v1[4])+q2*us2f(v2[4])+q3*us2f(v3[4]);
                c5 += q0*us2f(v0[5])+q1*us2f(v1[5])+q2*us2f(v2[5])+q3*us2f(v3[5]);
                c6 += q0*us2f(v0[6])+q1*us2f(v1[6])+q2*us2f(v2[6])+q3*us2f(v3[6]);
                c7 += q0*us2f(v0[7])+q1*us2f(v1[7])+q2*us2f(v2[7])+q3*us2f(v3[7]);
            }
        }
        for(; it < cnt; it++){
            int j0 = rdl_i(jl, it);
            float q0 = rdl_f(al, it);
            if(act){
                u16x8 v0 = ((const u16x8*)(x + (size_t)j0*XP))[lane];
                c0 += q0*us2f(v0[0]); c1 += q0*us2f(v0[1]); c2 += q0*us2f(v0[2]); c3 += q0*us2f(v0[3]);
                c4 += q0*us2f(v0[4]); c5 += q0*us2f(v0[5]); c6 += q0*us2f(v0[6]); c7 += q0*us2f(v0[7]);
            }
        }
    } else if(cnt > 64){
        float mx = -1e30f;
        for(int it=s0; it<s1; it++){
            float lg = p + ajv[clampi(adjj[it], NN)];
            lg = lg > 0 ? lg : 0.01f*lg;
            mx = fmaxf(mx, lg);
        }
        float ssum = 0.f;
        for(int it=s0; it<s1; it++){
            float lg = p + ajv[clampi(adjj[it], NN)];
            lg = lg > 0 ? lg : 0.01f*lg;
            ssum += __expf(lg - mx);
        }
        float rinv = __builtin_amdgcn_rcpf(ssum);
        for(int it=s0; it<s1; it++){
            int j = clampi(adjj[it], NN);
            float lg = p + ajv[j];
            lg = lg > 0 ? lg : 0.01f*lg;
            float aw = __expf(lg - mx)*rinv;
            if(act){
                u16x8 v0 = ((const u16x8*)(x + (size_t)j*XP))[lane];
                c0 += aw*us2f(v0[0]); c1 += aw*us2f(v0[1]); c2 += aw*us2f(v0[2]); c3 += aw*us2f(v0[3]);
                c4 += aw*us2f(v0[4]); c5 += aw*us2f(v0[5]); c6 += aw*us2f(v0[6]); c7 += aw*us2f(v0[7]);
            }
        }
    }
    float part = 0.f;
    if(act){
        const float4* f5 = (const float4*)(apad + 5*XP);
        const float4* f6 = (const float4*)(apad + 6*XP);
        float4 u0 = f5[2*lane], u1 = f5[2*lane+1];
        float4 g0 = f6[2*lane], g1 = f6[2*lane+1];
        part = xv[0]*u0.x + xv[1]*u0.y + xv[2]*u0.z + xv[3]*u0.w
             + xv[4]*u1.x + xv[5]*u1.y + xv[6]*u1.z + xv[7]*u1.w
             + fmaxf(c0,0.f)*g0.x + fmaxf(c1,0.f)*g0.y + fmaxf(c2,0.f)*g0.z + fmaxf(c3,0.f)*g0.w
             + fmaxf(c4,0.f)*g1.x + fmaxf(c5,0.f)*g1.y + fmaxf(c6,0.f)*g1.z + fmaxf(c7,0.f)*g1.w;
    }
    part = dpp_sum(part);
    if(lane == 0) out[n] = part + fcb[0];
}

extern "C" void kernel_launch(void* const* d_in, const int* in_sizes, int n_in,
                              void* d_out, int out_size, void* d_ws, size_t ws_size,
                              hipStream_t stream){
    const float* x_in = (const float*)d_in[0];
    const int*  ht   = (const int*)d_in[1];
    const int*  rel  = (const int*)d_in[2];
    const int*  ji   = (const int*)d_in[3];
    const float* hw1w=(const float*)d_in[5];  const float* hw1b=(const float*)d_in[6];
    const float* hw2w=(const float*)d_in[7];  const float* hw2b=(const float*)d_in[8];
    const float* tc1w=(const float*)d_in[9];  const float* tc1b=(const float*)d_in[10];
    const float* sr1w=(const float*)d_in[11]; const float* sr1b=(const float*)d_in[12];
    const float* wrw =(const float*)d_in[15]; const float* wrb =(const float*)d_in[16];
    const float* wr1w=(const float*)d_in[17]; const float* wr1b=(const float*)d_in[18];
    const float* wr2w=(const float*)d_in[19]; const float* wr2b=(const float*)d_in[20];
    const float* ahw =(const float*)d_in[21]; const float* ah1w=(const float*)d_in[22];
    const float* atw =(const float*)d_in[23];
    const float* ar1 =(const float*)d_in[24]; const float* ar2 =(const float*)d_in[25];
    const float* ar3 =(const float*)d_in[26];
    const float* aiw =(const float*)d_in[27]; const float* ajw =(const float*)d_in[28];
    const float* fcw =(const float*)d_in[29]; const float* fcb =(const float*)d_in[30];
    float* out = (float*)d_out;

    char* w = (char*)d_ws;
    auto alloc = [&](size_t bytes)->char*{ char* p = w; w += (bytes + 255)/256*256; return p; };
    bf16* xF = (bf16*)alloc((size_t)NN128*XP*2);    // 32 MB padded
    bf16* B  = (bf16*)alloc((size_t)NN128*XP*2);    // 32 MB padded; CSR tmp -> gcn/x1 -> rel tables
    char* Bc = (char*)B;
    int2* tmp_all = (int2*)(Bc);                      // 4 MB
    int2* tmp_h   = (int2*)(Bc + 4u*1024*1024);       // 2 MB
    int2* tmp_t   = (int2*)(Bc + 8u*1024*1024);       // 2 MB
    int2* tmp_r   = (int2*)(Bc + 12u*1024*1024);      // 2 MB
    bf16*  sbuf   = (bf16*)(Bc);                      // 10.01 MB (after CSR phase)
    float* RFpart = (float*)(Bc + 10u*1024*1024 + 512u*1024);  // 7.68 MB (RCH=32)
    bf16*  ER     = (bf16*)(Bc + 18u*1024*1024 + 512u*1024);   // 576 KB (bf16 padded rows)
    float* cvec   = (float*)(Bc + 19u*1024*1024 + 256u*1024);
    float* ajv    = (float*)(Bc + 19u*1024*1024 + 512u*1024);
    short* Wt1 = (short*)alloc((size_t)320*320*2);
    short* Wt2 = (short*)alloc((size_t)320*320*2);
    short* Wtc = (short*)alloc((size_t)128*320*2);
    float* apad = (float*)alloc((size_t)7*XP*4);
    float* dinv = (float*)alloc((size_t)NN*4);
    int* off_all=(int*)alloc((NN+1)*4);
    int* adj_all=(int*)alloc((size_t)NEA*4);
    int* off_h  =(int*)alloc((NN+1)*4);
    int* adj_h  =(int*)alloc((size_t)NE*4);
    int* off_t  =(int*)alloc((NN+1)*4);
    int* adj_t  =(int*)alloc((size_t)NE*4);
    int* off_r  =(int*)alloc((NR+1)*4);
    int* adj_r  =(int*)alloc((size_t)NE*4);
    int* bcnt   =(int*)alloc(512*4);
    int* gbase  =(int*)alloc(4*129*4);
    int* gcur   =(int*)alloc(4*128*4);

    hipMemsetAsync(bcnt, 0, 512*4, stream);
    k_prepc<<<dim3(XCB + TRB + APB + 4*BCNT_NB), dim3(256), 0, stream>>>(x_in, (ushort*)xF, hw1w, hw2w, tc1w,
                                                          Wt1, Wt2, Wtc,
                                                          ahw, atw, ah1w, ajw, aiw, fcw,
                                                          apad, bcnt, ji, ht, rel);
    k_bscan<<<dim3(1), dim3(512), 0, stream>>>(bcnt, gbase, gcur);
    k_bin<<<dim3((NEA+2047)/2048, 4), dim3(256), 0, stream>>>(ji, ht, rel, gcur,
                                                              tmp_all, tmp_h, tmp_t, tmp_r);
    k_place<<<dim3(NBN, 4), dim3(256), 0, stream>>>(gbase, tmp_all, tmp_h, tmp_t, tmp_r,
                                                    off_all, off_h, off_t, off_r,
                                                    adj_all, adj_h, adj_t, adj_r, dinv);

    // highway 1: B = gcn(xF); B = sig(xF@W1+b)*B + (1-sig)*xF
    k_gcn<<<dim3(NB4), dim3(256), 0, stream>>>(xF, B, off_all, adj_all, dinv);
    k_gemm_mfma<1><<<dim3((NN128/64)*5), dim3(256), 0, stream>>>(xF, Wt1, hw1b, B, xF, NN, XP, EHD, XP, 5);
    // highway 2
    k_gcn<<<dim3(NB4), dim3(256), 0, stream>>>(B, xF, off_all, adj_all, dinv);
    k_gemm_mfma<1><<<dim3((NN128/64)*5), dim3(256), 0, stream>>>(B, Wt2, hw2b, xF, B, NN, XP, EHD, XP, 5);
    // rel tables
    k_gemm_mfma<0><<<dim3((NN128/64)*2), dim3(256), 0, stream>>>(xF, Wtc, tc1b, sbuf, xF, NN, XP, THD, THD, 2);
    k_relsum2<<<dim3(NR, RCH), dim3(256), 0, stream>>>(sbuf, ht, off_r, adj_r, RFpart);
    k_reler<<<dim3(NR, 3), dim3(256), 0, stream>>>(RFpart, off_r, sr1w, sr1b,
                                                   wrw, wrb, wr1w, wr1b, wr2w, wr2b,
                                                   ar1, ar2, ar3, ER, cvec);
    // fused three r2e rounds + ajv
    k_r2e3<<<dim3(NB4), dim3(256), 0, stream>>>(xF, off_h, adj_h, off_t, adj_t, ER, cvec,
                                                apad, ajv);
    // final GAT + fc
    k_final<<<dim3(NB4), dim3(256), 0, stream>>>(xF, ajv, off_all, adj_all, apad, fcb, out);
}

// Round 14
// 586.625 us; speedup vs baseline: 1.0649x; 1.0649x over previous
//
#include <hip/hip_runtime.h>
#include <hip/hip_bf16.h>

typedef __hip_bfloat16 bf16;
typedef __attribute__((ext_vector_type(8))) short bf16x8_t;
typedef __attribute__((ext_vector_type(8))) unsigned short u16x8;
typedef __attribute__((ext_vector_type(4))) float f32x4_t;
typedef __attribute__((ext_vector_type(2))) float f32x2;

__device__ __forceinline__ float b2f(bf16 v){ return __bfloat162float(v); }
__device__ __forceinline__ bf16 f2b(float v){ return __float2bfloat16(v); }
__device__ __forceinline__ short tobits(float v){ bf16 b = f2b(v); return *(short*)&b; }
__device__ __forceinline__ float us2f(ushort u){ return __uint_as_float(((unsigned)u)<<16); }
__device__ __forceinline__ ushort f2us(float v){ bf16 b = f2b(v); return *(ushort*)&b; }
// exact bf16-pair -> f32x2 (lo = w<<16, hi = w & 0xffff0000)
__device__ __forceinline__ f32x2 bf2x2(unsigned w){
    f32x2 r; r[0] = __uint_as_float(w << 16); r[1] = __uint_as_float(w & 0xffff0000u); return r;
}

#define NN 50000
#define NN128 50048   // NN rounded so GEMM staging needs no M-guard (782*64)
#define NE 250000
#define NEA 500000
#define NR 300
#define EHD 300
#define THD 100
#define RHD 100
#define XP 320      // padded row stride for 300-wide rows (bf16 rows -> 640B, 16B aligned)
#define ERP 320     // padded ER row stride (bf16: 640B rows)
#define RCH 32      // rel-sum chunks per relation (serial chains short, head+tail ILP kept)
#define NBN 98      // node buckets (512 wide)
#define NBR 75      // rel buckets (4 wide)
#define PREP_NB 8782  // ceil((NN*40 + 2*320*320 + 128*320 + 7*320)/256)
#define BCNT_NB 245   // ceil(NEA/2048)
#define NB4 12500     // wave-per-node blocks (4 nodes each)

__device__ __forceinline__ int clampi(int v, int n){ return ((unsigned)v < (unsigned)n) ? v : 0; }

// wave-uniform lane broadcast
__device__ __forceinline__ int rdl_i(int v, int l){ return __builtin_amdgcn_readlane(v, l); }
__device__ __forceinline__ float rdl_f(float v, int l){ return __int_as_float(__builtin_amdgcn_readlane(__float_as_int(v), l)); }

// async global->LDS, 16B per lane (dest = wave-uniform base + lane*16)
typedef const __attribute__((address_space(1))) unsigned int* gas1_t;
typedef __attribute__((address_space(3))) unsigned int* las3_t;
__device__ __forceinline__ void glds16(const void* g, void* l){
    __builtin_amdgcn_global_load_lds((gas1_t)g, (las3_t)l, 16, 0, 0);
}

// ---------- DPP wave reductions ----------
__device__ __forceinline__ float dpp_sum(float x){
    int v;
    v = __builtin_amdgcn_update_dpp(0, __float_as_int(x), 0x111, 0xf, 0xf, true); x += __int_as_float(v);
    v = __builtin_amdgcn_update_dpp(0, __float_as_int(x), 0x112, 0xf, 0xf, true); x += __int_as_float(v);
    v = __builtin_amdgcn_update_dpp(0, __float_as_int(x), 0x114, 0xf, 0xf, true); x += __int_as_float(v);
    v = __builtin_amdgcn_update_dpp(0, __float_as_int(x), 0x118, 0xf, 0xf, true); x += __int_as_float(v);
    v = __builtin_amdgcn_update_dpp(0, __float_as_int(x), 0x142, 0xf, 0xf, true); x += __int_as_float(v);
    v = __builtin_amdgcn_update_dpp(0, __float_as_int(x), 0x143, 0xf, 0xf, true); x += __int_as_float(v);
    return __int_as_float(__builtin_amdgcn_readlane(__float_as_int(x), 63));
}
__device__ __forceinline__ float dpp_max(float x){
    int v;
    v = __builtin_amdgcn_update_dpp(__float_as_int(x), __float_as_int(x), 0x111, 0xf, 0xf, false); x = fmaxf(x, __int_as_float(v));
    v = __builtin_amdgcn_update_dpp(__float_as_int(x), __float_as_int(x), 0x112, 0xf, 0xf, false); x = fmaxf(x, __int_as_float(v));
    v = __builtin_amdgcn_update_dpp(__float_as_int(x), __float_as_int(x), 0x114, 0xf, 0xf, false); x = fmaxf(x, __int_as_float(v));
    v = __builtin_amdgcn_update_dpp(__float_as_int(x), __float_as_int(x), 0x118, 0xf, 0xf, false); x = fmaxf(x, __int_as_float(v));
    v = __builtin_amdgcn_update_dpp(__float_as_int(x), __float_as_int(x), 0x142, 0xf, 0xf, false); x = fmaxf(x, __int_as_float(v));
    v = __builtin_amdgcn_update_dpp(__float_as_int(x), __float_as_int(x), 0x143, 0xf, 0xf, false); x = fmaxf(x, __int_as_float(v));
    return __int_as_float(__builtin_amdgcn_readlane(__float_as_int(x), 63));
}

// ---------- fused prep + bucket-count ----------
__global__ __launch_bounds__(256) void k_prepc(const float* __restrict__ xin, ushort* __restrict__ xFu,
                       const float* __restrict__ hw1w, const float* __restrict__ hw2w,
                       const float* __restrict__ tc1w,
                       short* __restrict__ Wt1, short* __restrict__ Wt2, short* __restrict__ Wtc,
                       const float* __restrict__ ahw, const float* __restrict__ atw,
                       const float* __restrict__ ah1w, const float* __restrict__ ajw,
                       const float* __restrict__ aiw, const float* __restrict__ fcw,
                       float* __restrict__ apad, int* __restrict__ bcnt,
                       const int* __restrict__ ji, const int* __restrict__ ht,
                       const int* __restrict__ rel){
    int blk = blockIdx.x, tid = threadIdx.x;
    __shared__ int h[128];
    if(blk >= PREP_NB){
        int eb = blk - PREP_NB;
        int s = eb/BCNT_NB, bx = eb - s*BCNT_NB;
        int n_s = (s == 0) ? NEA : NE;
        int base_e = bx*2048;
        if(base_e >= n_s) return;
        int shift = (s < 3) ? 9 : 2;
        if(tid < 128) h[tid] = 0;
        __syncthreads();
        #pragma unroll
        for(int u=0;u<8;u++){
            int e = base_e + u*256 + tid;
            if(e < n_s){
                int key;
                if(s == 0) key = clampi(ji[NEA + e], NN);
                else if(s == 1) key = clampi(ht[e], NN);
                else if(s == 2) key = clampi(ht[NE + e], NN);
                else key = clampi(rel[e], NR);
                atomicAdd(&h[key >> shift], 1);
            }
        }
        __syncthreads();
        if(tid < 128 && h[tid] > 0) atomicAdd(&bcnt[s*128 + tid], h[tid]);
        return;
    }
    int i = blk*256 + tid;
    const int NC = NN*40;
    const int S1 = NC + 320*320;
    const int S2 = S1 + 320*320;
    const int S3 = S2 + 128*320;
    const int S4 = S3 + 7*XP;
    if(i < NC){
        int nrow = i/40, c8 = i - nrow*40, c = c8*8;
        ushort o[8];
        if(c + 8 <= EHD){
            const float4* src = (const float4*)(xin + (size_t)nrow*EHD + c);
            float4 v0 = src[0], v1 = src[1];
            o[0]=f2us(v0.x); o[1]=f2us(v0.y); o[2]=f2us(v0.z); o[3]=f2us(v0.w);
            o[4]=f2us(v1.x); o[5]=f2us(v1.y); o[6]=f2us(v1.z); o[7]=f2us(v1.w);
        } else {
            #pragma unroll
            for(int k=0;k<8;k++){
                int cc = c + k;
                o[k] = (cc < EHD) ? f2us(xin[(size_t)nrow*EHD + cc]) : (ushort)0;
            }
        }
        u16x8 w;
        #pragma unroll
        for(int k=0;k<8;k++) w[k] = o[k];
        *(u16x8*)(xFu + (size_t)nrow*XP + c) = w;
    } else if(i < S1){
        int ii = i - NC; int n = ii/320, k = ii - n*320;
        Wt1[ii] = (n < EHD && k < EHD) ? tobits(hw1w[(size_t)k*EHD + n]) : (short)0;
    } else if(i < S2){
        int ii = i - S1; int n = ii/320, k = ii - n*320;
        Wt2[ii] = (n < EHD && k < EHD) ? tobits(hw2w[(size_t)k*EHD + n]) : (short)0;
    } else if(i < S3){
        int ii = i - S2; int n = ii/320, k = ii - n*320;
        Wtc[ii] = (n < THD && k < EHD) ? tobits(tc1w[(size_t)k*THD + n]) : (short)0;
    } else if(i < S4){
        int ii = i - S3; int v = ii/XP, c = ii - v*XP;
        float val = 0.f;
        if(c < EHD){
            const float* src = (v==0)?ahw:(v==1)?atw:(v==2)?ah1w:(v==3)?ajw:(v==4)?aiw:
                               (v==5)? fcw : (fcw + EHD);
            val = src[c];
        }
        apad[ii] = val;
    }
}

// ---------- segmented scan of bucket counts -> gbase[4][129], gcur[4][128] ----------
__global__ void k_bscan(const int* __restrict__ bcnt, int* __restrict__ gbase, int* __restrict__ gcur){
    __shared__ int lds[512];
    int tid = threadIdx.x;   // 512
    int v = bcnt[tid];
    lds[tid] = v; __syncthreads();
    for(int st=1; st<128; st<<=1){
        int add = ((tid & 127) >= st) ? lds[tid-st] : 0;
        __syncthreads();
        lds[tid] += add;
        __syncthreads();
    }
    int s = tid >> 7, b = tid & 127;
    int excl = lds[tid] - v;
    gbase[s*129 + b] = excl;
    gcur[s*128 + b] = excl;
    if(b == 127) gbase[s*129 + 128] = lds[tid];
}

// ---------- Phase C: LDS-staged binning ----------
__global__ __launch_bounds__(256) void k_bin(const int* __restrict__ ji, const int* __restrict__ ht,
                      const int* __restrict__ rel, int* __restrict__ gcur,
                      int2* __restrict__ t0, int2* __restrict__ t1,
                      int2* __restrict__ t2, int2* __restrict__ t3){
    int s = blockIdx.y;
    int n_s = (s == 0) ? NEA : NE;
    int base_e = blockIdx.x*2048;
    if(base_e >= n_s) return;
    int shift = (s < 3) ? 9 : 2;
    int tid = threadIdx.x;
    __shared__ int cnt[128], lof[128], base[128];
    __shared__ int2 buf[2048];
    if(tid < 128) cnt[tid] = 0;
    __syncthreads();
    int kk[8], pp[8], bb[8], ss[8];
    #pragma unroll
    for(int u=0;u<8;u++){
        int e = base_e + u*256 + tid;
        bb[u] = -1;
        if(e < n_s){
            int key, pay;
            if(s == 0){ key = clampi(ji[NEA + e], NN); pay = clampi(ji[e], NN); }
            else if(s == 1){ key = clampi(ht[e], NN); pay = clampi(rel[e], NR); }
            else if(s == 2){ key = clampi(ht[NE + e], NN); pay = clampi(rel[e], NR); }
            else { key = clampi(rel[e], NR); pay = e; }
            int b = key >> shift;
            kk[u] = key; pp[u] = pay; bb[u] = b;
            ss[u] = atomicAdd(&cnt[b], 1);
        }
    }
    __syncthreads();
    if(tid == 0){
        int run = 0;
        for(int b=0;b<128;b++){ lof[b] = run; run += cnt[b]; }
    }
    __syncthreads();
    #pragma unroll
    for(int u=0;u<8;u++){
        if(bb[u] >= 0){
            int pos = lof[bb[u]] + ss[u];
            buf[pos] = make_int2(kk[u], pp[u]);
        }
    }
    __syncthreads();
    if(tid < 128 && cnt[tid] > 0) base[tid] = atomicAdd(&gcur[s*128 + tid], cnt[tid]);
    __syncthreads();
    int2* tmp = (s==0) ? t0 : (s==1) ? t1 : (s==2) ? t2 : t3;
    int total = lof[127] + cnt[127];
    for(int idx=tid; idx<total; idx+=256){
        int2 kp = buf[idx];
        int b = kp.x >> shift;
        tmp[base[b] + (idx - lof[b])] = kp;
    }
}

// ---------- Phase D: windowed CSR fill ----------
__global__ __launch_bounds__(256) void k_place(const int* __restrict__ gbase,
                        const int2* __restrict__ t0, const int2* __restrict__ t1,
                        const int2* __restrict__ t2, const int2* __restrict__ t3,
                        int* __restrict__ off_all, int* __restrict__ off_h,
                        int* __restrict__ off_t, int* __restrict__ off_r,
                        int* __restrict__ adj_all, int* __restrict__ adj_h,
                        int* __restrict__ adj_t, int* __restrict__ adj_r,
                        float* __restrict__ dinv){
    int s = blockIdx.y, b = blockIdx.x;
    int NB = (s < 3) ? NBN : NBR;
    if(b >= NB) return;
    int W = (s < 3) ? 512 : 4;
    int len = (s < 3) ? NN : NR;
    const int2* tmp = (s==0) ? t0 : (s==1) ? t1 : (s==2) ? t2 : t3;
    int* off = (s==0) ? off_all : (s==1) ? off_h : (s==2) ? off_t : off_r;
    int* adj = (s==0) ? adj_all : (s==1) ? adj_h : (s==2) ? adj_t : adj_r;
    int node0 = b*W;
    int node1 = node0 + W; if(node1 > len) node1 = len;
    int nloc = node1 - node0;
    int wstart = gbase[s*129 + b], wend = gbase[s*129 + b + 1];
    __shared__ int hist[512];
    __shared__ int cur[512];
    __shared__ int sb[256];
    int tid = threadIdx.x;
    for(int k=tid; k<nloc; k+=256) hist[k] = 0;
    __syncthreads();
    for(int idx = wstart + tid; idx < wend; idx += 256){
        int local = tmp[idx].x - node0;
        if((unsigned)local < (unsigned)nloc) atomicAdd(&hist[local], 1);
    }
    __syncthreads();
    int v0 = (2*tid   < nloc) ? hist[2*tid]   : 0;
    int v1 = (2*tid+1 < nloc) ? hist[2*tid+1] : 0;
    int ps = v0 + v1;
    sb[tid] = ps; __syncthreads();
    for(int st=1; st<256; st<<=1){
        int add = (tid >= st) ? sb[tid-st] : 0;
        __syncthreads();
        sb[tid] += add;
        __syncthreads();
    }
    int excl = sb[tid] - ps;
    if(2*tid < nloc){
        int o = wstart + excl;
        off[node0 + 2*tid] = o;
        cur[2*tid] = o;
        if(s == 0) dinv[node0 + 2*tid] = v0 > 0 ? rsqrtf((float)v0) : 0.f;
    }
    if(2*tid+1 < nloc){
        int o = wstart + excl + v0;
        off[node0 + 2*tid+1] = o;
        cur[2*tid+1] = o;
        if(s == 0) dinv[node0 + 2*tid+1] = v1 > 0 ? rsqrtf((float)v1) : 0.f;
    }
    if(b == NB-1 && tid == 0) off[len] = gbase[s*129 + 128];
    __syncthreads();
    for(int idx = wstart + tid; idx < wend; idx += 256){
        int2 kp = tmp[idx];
        int local = kp.x - node0;
        if((unsigned)local < (unsigned)nloc){
            int slot = atomicAdd(&cur[local], 1);
            adj[slot] = kp.y;
        }
    }
}

// ---------- GCN gather: wave per node, 16B row loads, readlane broadcasts ----------
__global__ void k_gcn(const bf16* __restrict__ xs, bf16* __restrict__ xd,
                      const int* __restrict__ off, const int* __restrict__ adjj,
                      const float* __restrict__ dinv){
    int wid = threadIdx.x >> 6, lane = threadIdx.x & 63;
    int n = blockIdx.x*4 + wid;
    if(n >= NN) return;
    float di = dinv[n];
    int s0 = off[n], s1 = off[n+1], cnt = s1 - s0;
    bool act = lane < 40;
    float c0=0,c1=0,c2=0,c3=0,c4=0,c5=0,c6=0,c7=0;
    if(cnt > 0 && cnt <= 64){
        int jl = (lane < cnt) ? clampi(adjj[s0+lane], NN) : 0;
        float dl = (lane < cnt) ? dinv[jl] : 0.f;
        int it = 0;
        for(; it+4 <= cnt; it += 4){
            int j0=rdl_i(jl,it), j1=rdl_i(jl,it+1), j2=rdl_i(jl,it+2), j3=rdl_i(jl,it+3);
            float n0=di*rdl_f(dl,it), n1=di*rdl_f(dl,it+1), n2=di*rdl_f(dl,it+2), n3=di*rdl_f(dl,it+3);
            if(act){
                u16x8 v0 = ((const u16x8*)(xs + (size_t)j0*XP))[lane];
                u16x8 v1 = ((const u16x8*)(xs + (size_t)j1*XP))[lane];
                u16x8 v2 = ((const u16x8*)(xs + (size_t)j2*XP))[lane];
                u16x8 v3 = ((const u16x8*)(xs + (size_t)j3*XP))[lane];
                c0 += n0*us2f(v0[0])+n1*us2f(v1[0])+n2*us2f(v2[0])+n3*us2f(v3[0]);
                c1 += n0*us2f(v0[1])+n1*us2f(v1[1])+n2*us2f(v2[1])+n3*us2f(v3[1]);
                c2 += n0*us2f(v0[2])+n1*us2f(v1[2])+n2*us2f(v2[2])+n3*us2f(v3[2]);
                c3 += n0*us2f(v0[3])+n1*us2f(v1[3])+n2*us2f(v2[3])+n3*us2f(v3[3]);
                c4 += n0*us2f(v0[4])+n1*us2f(v1[4])+n2*us2f(v2[4])+n3*us2f(v3[4]);
                c5 += n0*us2f(v0[5])+n1*us2f(v1[5])+n2*us2f(v2[5])+n3*us2f(v3[5]);
                c6 += n0*us2f(v0[6])+n1*us2f(v1[6])+n2*us2f(v2[6])+n3*us2f(v3[6]);
                c7 += n0*us2f(v0[7])+n1*us2f(v1[7])+n2*us2f(v2[7])+n3*us2f(v3[7]);
            }
        }
        for(; it < cnt; it++){
            int j0 = rdl_i(jl, it);
            float n0 = di*rdl_f(dl, it);
            if(act){
                u16x8 v0 = ((const u16x8*)(xs + (size_t)j0*XP))[lane];
                c0 += n0*us2f(v0[0]); c1 += n0*us2f(v0[1]); c2 += n0*us2f(v0[2]); c3 += n0*us2f(v0[3]);
                c4 += n0*us2f(v0[4]); c5 += n0*us2f(v0[5]); c6 += n0*us2f(v0[6]); c7 += n0*us2f(v0[7]);
            }
        }
    } else if(cnt > 64){
        for(int it=s0; it<s1; it++){
            int j = clampi(adjj[it], NN);
            float nr = di * dinv[j];
            if(act){
                u16x8 v0 = ((const u16x8*)(xs + (size_t)j*XP))[lane];
                c0 += nr*us2f(v0[0]); c1 += nr*us2f(v0[1]); c2 += nr*us2f(v0[2]); c3 += nr*us2f(v0[3]);
                c4 += nr*us2f(v0[4]); c5 += nr*us2f(v0[5]); c6 += nr*us2f(v0[6]); c7 += nr*us2f(v0[7]);
            }
        }
    }
    if(act){
        u16x8 w;
        w[0]=f2us(fmaxf(c0,0.f)); w[1]=f2us(fmaxf(c1,0.f)); w[2]=f2us(fmaxf(c2,0.f)); w[3]=f2us(fmaxf(c3,0.f));
        w[4]=f2us(fmaxf(c4,0.f)); w[5]=f2us(fmaxf(c5,0.f)); w[6]=f2us(fmaxf(c6,0.f)); w[7]=f2us(fmaxf(c7,0.f));
        ((u16x8*)(xd + (size_t)n*XP))[lane] = w;
    }
}

// ---------- MFMA GEMM: 64x64 tile, glds staging + XOR swizzle, 1D grid with
// bijective XCD-chunk swizzle + column-fastest panel decode for A-panel L2 reuse ----------
template<int MODE>
__global__ __launch_bounds__(256) void k_gemm_mfma(const bf16* __restrict__ X,
                       const short* __restrict__ Wt, const float* __restrict__ bias,
                       bf16* __restrict__ out, const bf16* __restrict__ Xprev,
                       int M, int K, int Ncols, int ldOut, int ncb){
    __shared__ short As[64*32];
    __shared__ short Bs[64*32];
    int tid = threadIdx.x;
    int bid = blockIdx.x;
    int nwg = gridDim.x;
    int xcd = bid & 7, idx = bid >> 3;
    int q = nwg >> 3, rr = nwg & 7;
    int logical = (xcd < rr ? xcd*(q+1) : rr*(q+1) + (xcd-rr)*q) + idx;
    int pan = logical / ncb;
    int bm = pan*64, bn = (logical - pan*ncb)*64;
    int wid = tid>>6, lane = tid&63;
    int wm = (wid&1)*32, wn = (wid>>1)*32;
    int lm = lane&15, lq = lane>>4;
    f32x4_t acc00={0,0,0,0}, acc01={0,0,0,0}, acc10={0,0,0,0}, acc11={0,0,0,0};
    int srow = tid>>2, ssl = tid&3;
    int ssl_sw = ssl ^ ((srow>>1)&3);
    short* ldsA = As + (size_t)(wid*64)*8;
    short* ldsB = Bs + (size_t)(wid*64)*8;
    const bf16*  gA = X  + (size_t)(bm + srow)*K + ssl_sw*8;
    const short* gB = Wt + (size_t)(bn + srow)*K + ssl_sw*8;
    for(int k0=0; k0<K; k0+=32){
        glds16(gA + k0, ldsA);
        glds16(gB + k0, ldsB);
        __syncthreads();
        int ra0 = wm + lm, ra1 = wm + 16 + lm;
        int rb0 = wn + lm, rb1 = wn + 16 + lm;
        bf16x8_t a0 = *(const bf16x8_t*)(As + ra0*32 + ((lq ^ ((ra0>>1)&3))*8));
        bf16x8_t a1 = *(const bf16x8_t*)(As + ra1*32 + ((lq ^ ((ra1>>1)&3))*8));
        bf16x8_t b0 = *(const bf16x8_t*)(Bs + rb0*32 + ((lq ^ ((rb0>>1)&3))*8));
        bf16x8_t b1 = *(const bf16x8_t*)(Bs + rb1*32 + ((lq ^ ((rb1>>1)&3))*8));
        acc00 = __builtin_amdgcn_mfma_f32_16x16x32_bf16(a0, b0, acc00, 0, 0, 0);
        acc01 = __builtin_amdgcn_mfma_f32_16x16x32_bf16(a0, b1, acc01, 0, 0, 0);
        acc10 = __builtin_amdgcn_mfma_f32_16x16x32_bf16(a1, b0, acc10, 0, 0, 0);
        acc11 = __builtin_amdgcn_mfma_f32_16x16x32_bf16(a1, b1, acc11, 0, 0, 0);
        __syncthreads();
    }
    #pragma unroll
    for(int tm=0;tm<2;tm++){
        #pragma unroll
        for(int tn=0;tn<2;tn++){
            f32x4_t a = tm==0 ? (tn==0 ? acc00 : acc01) : (tn==0 ? acc10 : acc11);
            int gn = bn + wn + tn*16 + lm;
            if(gn >= Ncols) continue;
            float bi = bias[gn];
            #pragma unroll
            for(int r2=0;r2<4;r2++){
                int gm = bm + wm + tm*16 + lq*4 + r2;
                if(gm >= M) continue;
                float t = a[r2] + bi;
                size_t p = (size_t)gm*ldOut + gn;
                if(MODE == 0){
                    out[p] = f2b(t);
                } else {
                    float g = __builtin_amdgcn_rcpf(1.f + __expf(-t));
                    out[p] = f2b(g*b2f(out[p]) + (1.f - g)*b2f(Xprev[p]));
                }
            }
        }
    }
}

// ---------- chunked per-relation sums into private slabs (RCH=32, head+tail ILP) ----------
__global__ void k_relsum2(const bf16* __restrict__ s, const int* __restrict__ ht,
                          const int* __restrict__ off_r, const int* __restrict__ adj_r,
                          float* __restrict__ RFpart){
    int r = blockIdx.x, c = blockIdx.y, d = threadIdx.x;
    if(d >= THD) return;
    int s0 = off_r[r], s1 = off_r[r+1];
    int cnt = s1 - s0;
    float ah = 0.f, at2 = 0.f;
    if(cnt > 0){
        int per = (cnt + RCH - 1)/RCH;
        int lo = s0 + c*per, hi = lo + per; if(hi > s1) hi = s1;
        for(int it=lo; it<hi; it++){
            int e = clampi(adj_r[it], NE);
            int hh = clampi(ht[e], NN), tt = clampi(ht[NE + e], NN);
            ah  += b2f(s[(size_t)hh*THD + d]);
            at2 += b2f(s[(size_t)tt*THD + d]);
        }
    }
    size_t base = (size_t)(r*RCH + c)*2*THD;
    RFpart[base + d] = ah;
    RFpart[base + THD + d] = at2;
}

// ---------- fused: slab-reduce -> means + x_res2 (in LDS) -> ER (bf16) + cvec ----------
__global__ void k_reler(const float* __restrict__ RFpart, const int* __restrict__ off_r,
                        const float* __restrict__ sr1w, const float* __restrict__ sr1b,
                        const float* w0, const float* b0, const float* w1, const float* b1,
                        const float* w2, const float* b2,
                        const float* ar1, const float* ar2, const float* ar3,
                        bf16* __restrict__ ER, float* __restrict__ cvec){
    int r = blockIdx.x, kk = blockIdx.y;
    const float* w = kk==0 ? w0 : (kk==1 ? w1 : w2);
    const float* b = kk==0 ? b0 : (kk==1 ? b1 : b2);
    const float* a = kk==0 ? ar1 : (kk==1 ? ar2 : ar3);
    int tid = threadIdx.x;
    __shared__ float rfs[EHD];
    int cnt = off_r[r+1] - off_r[r];
    float inv = 1.f/(float)(cnt > 1 ? cnt : 1);
    for(int d=tid; d<2*THD; d+=256){
        float sacc = 0.f;
        #pragma unroll
        for(int c=0;c<RCH;c++) sacc += RFpart[(size_t)(r*RCH + c)*2*THD + d];
        rfs[THD + d] = sacc*inv;
    }
    __syncthreads();
    if(tid < RHD){
        float v = 0.f;
        if(cnt > 0){
            v = sr1b[tid];
            for(int k2=0; k2<2*THD; k2++) v += rfs[THD + k2] * sr1w[k2*RHD + tid];
        }
        rfs[tid] = v;
    }
    __syncthreads();
    float pd = 0.f;
    for(int o = tid; o < ERP; o += 256){
        float v = 0.f;
        if(o < EHD){
            v = b[o];
            for(int d=0; d<EHD; d++) v += rfs[d] * w[(size_t)d*EHD + o];
            pd += v * a[o];
        }
        ER[((size_t)kk*NR + r)*ERP + o] = f2b(v);
    }
    __shared__ float red[4];
    pd = dpp_sum(pd);
    if((tid & 63) == 0) red[tid>>6] = pd;
    __syncthreads();
    if(tid == 0) cvec[kk*NR + r] = red[0]+red[1]+red[2]+red[3];
}

// ---------- one r2e round; bf16 ER gather, packed f32x2 accumulation ----------
__device__ __forceinline__ void r2e_round(float* xv, bool act, int lane, int s0, int s1,
        int rl, float cval,
        const int* __restrict__ adjrel, const bf16* __restrict__ ERk,
        const float* __restrict__ ck, const float* __restrict__ an){
    float p = 0.f;
    if(act){
        const float4* a4 = (const float4*)an;
        float4 a0 = a4[2*lane], a1 = a4[2*lane+1];
        p = xv[0]*a0.x + xv[1]*a0.y + xv[2]*a0.z + xv[3]*a0.w
          + xv[4]*a1.x + xv[5]*a1.y + xv[6]*a1.z + xv[7]*a1.w;
    }
    p = dpp_sum(p);
    int cnt = s1 - s0;
    if(cnt <= 0) return;
    f32x2 a01={0,0}, a23={0,0}, a45={0,0}, a67={0,0};
    if(cnt <= 64){
        float lg = p + cval;
        lg = lg > 0 ? lg : 0.01f*lg;
        float mx = dpp_max((lane < cnt) ? lg : -1e30f);
        float ex = (lane < cnt) ? __expf(lg - mx) : 0.f;
        float al = ex * __builtin_amdgcn_rcpf(dpp_sum(ex));
        int it = 0;
        for(; it+4 <= cnt; it += 4){
            int r0i = rdl_i(rl, it),   r1i = rdl_i(rl, it+1);
            int r2i = rdl_i(rl, it+2), r3i = rdl_i(rl, it+3);
            float q0 = rdl_f(al, it),   q1 = rdl_f(al, it+1);
            float q2 = rdl_f(al, it+2), q3 = rdl_f(al, it+3);
            if(act){
                uint4 e0 = ((const uint4*)(ERk + (size_t)r0i*ERP))[lane];
                uint4 e1 = ((const uint4*)(ERk + (size_t)r1i*ERP))[lane];
                uint4 e2 = ((const uint4*)(ERk + (size_t)r2i*ERP))[lane];
                uint4 e3 = ((const uint4*)(ERk + (size_t)r3i*ERP))[lane];
                a01 += q0*bf2x2(e0.x) + q1*bf2x2(e1.x) + q2*bf2x2(e2.x) + q3*bf2x2(e3.x);
                a23 += q0*bf2x2(e0.y) + q1*bf2x2(e1.y) + q2*bf2x2(e2.y) + q3*bf2x2(e3.y);
                a45 += q0*bf2x2(e0.z) + q1*bf2x2(e1.z) + q2*bf2x2(e2.z) + q3*bf2x2(e3.z);
                a67 += q0*bf2x2(e0.w) + q1*bf2x2(e1.w) + q2*bf2x2(e2.w) + q3*bf2x2(e3.w);
            }
        }
        for(; it < cnt; it++){
            int r0i = rdl_i(rl, it);
            float q0 = rdl_f(al, it);
            if(act){
                uint4 e0 = ((const uint4*)(ERk + (size_t)r0i*ERP))[lane];
                a01 += q0*bf2x2(e0.x); a23 += q0*bf2x2(e0.y);
                a45 += q0*bf2x2(e0.z); a67 += q0*bf2x2(e0.w);
            }
        }
    } else {
        float mx = -1e30f;
        for(int it=s0; it<s1; it++){
            float lg = p + ck[clampi(adjrel[it], NR)];
            lg = lg > 0 ? lg : 0.01f*lg;
            mx = fmaxf(mx, lg);
        }
        float ssum = 0.f;
        for(int it=s0; it<s1; it++){
            float lg = p + ck[clampi(adjrel[it], NR)];
            lg = lg > 0 ? lg : 0.01f*lg;
            ssum += __expf(lg - mx);
        }
        float rinv = __builtin_amdgcn_rcpf(ssum);
        for(int it=s0; it<s1; it++){
            int r = clampi(adjrel[it], NR);
            float lg = p + ck[r];
            lg = lg > 0 ? lg : 0.01f*lg;
            float aw = __expf(lg - mx)*rinv;
            if(act){
                uint4 e0 = ((const uint4*)(ERk + (size_t)r*ERP))[lane];
                a01 += aw*bf2x2(e0.x); a23 += aw*bf2x2(e0.y);
                a45 += aw*bf2x2(e0.z); a67 += aw*bf2x2(e0.w);
            }
        }
    }
    xv[0] += fmaxf(a01[0],0.f); xv[1] += fmaxf(a01[1],0.f);
    xv[2] += fmaxf(a23[0],0.f); xv[3] += fmaxf(a23[1],0.f);
    xv[4] += fmaxf(a45[0],0.f); xv[5] += fmaxf(a45[1],0.f);
    xv[6] += fmaxf(a67[0],0.f); xv[7] += fmaxf(a67[1],0.f);
}

// ---------- fused: three r2e rounds + ajv ----------
__global__ void k_r2e3(bf16* __restrict__ x,
                       const int* __restrict__ off_h, const int* __restrict__ adj_h,
                       const int* __restrict__ off_t, const int* __restrict__ adj_t,
                       const bf16* __restrict__ ER, const float* __restrict__ cvec,
                       const float* __restrict__ apad, float* __restrict__ ajv){
    int wid = threadIdx.x >> 6, lane = threadIdx.x & 63;
    int n = blockIdx.x*4 + wid;
    if(n >= NN) return;
    bool act = lane < 40;
    u16x8* xr = (u16x8*)(x + (size_t)n*XP);
    float xv[8];
    if(act){
        u16x8 v = xr[lane];
        #pragma unroll
        for(int k=0;k<8;k++) xv[k] = us2f(v[k]);
    } else {
        #pragma unroll
        for(int k=0;k<8;k++) xv[k] = 0.f;
    }
    int h0 = off_h[n], h1 = off_h[n+1];
    int t0_ = off_t[n], t1_ = off_t[n+1];
    int hcnt = h1 - h0, tcnt = t1_ - t0_;
    int rlh = (hcnt > 0 && hcnt <= 64 && lane < hcnt) ? clampi(adj_h[h0+lane], NR) : 0;
    int rlt = (tcnt > 0 && tcnt <= 64 && lane < tcnt) ? clampi(adj_t[t0_+lane], NR) : 0;
    float ch1 = cvec[rlh], ctv = cvec[NR + rlt], ch3 = cvec[2*NR + rlh];
    r2e_round(xv, act, lane, h0, h1, rlh, ch1, adj_h, ER,                    cvec,      apad);
    r2e_round(xv, act, lane, t0_, t1_, rlt, ctv, adj_t, ER + (size_t)NR*ERP, cvec+NR,   apad + XP);
    r2e_round(xv, act, lane, h0, h1, rlh, ch3, adj_h, ER + (size_t)2*NR*ERP, cvec+2*NR, apad + 2*XP);
    {
        float p = 0.f;
        if(act){
            const float4* a4 = (const float4*)(apad + 3*XP);
            float4 a0 = a4[2*lane], a1 = a4[2*lane+1];
            p = xv[0]*a0.x + xv[1]*a0.y + xv[2]*a0.z + xv[3]*a0.w
              + xv[4]*a1.x + xv[5]*a1.y + xv[6]*a1.z + xv[7]*a1.w;
        }
        p = dpp_sum(p);
        if(lane == 0) ajv[n] = p;
    }
    if(act){
        u16x8 w;
        #pragma unroll
        for(int k=0;k<8;k++) w[k] = f2us(xv[k]);
        xr[lane] = w;
    }
}

// ---------- final GAT + fc; 4-edge gather ----------
__global__ void k_final(const bf16* __restrict__ x, const float* __restrict__ ajv,
                        const int* __restrict__ off, const int* __restrict__ adjj,
                        const float* __restrict__ apad, const float* __restrict__ fcb,
                        float* __restrict__ out){
    int wid = threadIdx.x >> 6, lane = threadIdx.x & 63;
    int n = blockIdx.x*4 + wid;
    if(n >= NN) return;
    bool act = lane < 40;
    float xv[8];
    if(act){
        u16x8 v = ((const u16x8*)(x + (size_t)n*XP))[lane];
        #pragma unroll
        for(int k=0;k<8;k++) xv[k] = us2f(v[k]);
    } else {
        #pragma unroll
        for(int k=0;k<8;k++) xv[k] = 0.f;
    }
    float p = 0.f;
    if(act){
        const float4* a4 = (const float4*)(apad + 4*XP);
        float4 a0 = a4[2*lane], a1 = a4[2*lane+1];
        p = xv[0]*a0.x + xv[1]*a0.y + xv[2]*a0.z + xv[3]*a0.w
          + xv[4]*a1.x + xv[5]*a1.y + xv[6]*a1.z + xv[7]*a1.w;
    }
    p = dpp_sum(p);
    int s0 = off[n], s1 = off[n+1], cnt = s1 - s0;
    float c0=0,c1=0,c2=0,c3=0,c4=0,c5=0,c6=0,c7=0;
    if(cnt > 0 && cnt <= 64){
        int jl = (lane < cnt) ? clampi(adjj[s0+lane], NN) : 0;
        float av = (lane < cnt) ? ajv[jl] : 0.f;
        float lg = p + av;
        lg = lg > 0 ? lg : 0.01f*lg;
        float mx = dpp_max((lane < cnt) ? lg : -1e30f);
        float ex = (lane < cnt) ? __expf(lg - mx) : 0.f;
        float al = ex * __builtin_amdgcn_rcpf(dpp_sum(ex));
        int it = 0;
        for(; it+4 <= cnt; it += 4){
            int j0=rdl_i(jl,it), j1=rdl_i(jl,it+1), j2=rdl_i(jl,it+2), j3=rdl_i(jl,it+3);
            float q0=rdl_f(al,it), q1=rdl_f(al,it+1), q2=rdl_f(al,it+2), q3=rdl_f(al,it+3);
            if(act){
                u16x8 v0 = ((const u16x8*)(x + (size_t)j0*XP))[lane];
                u16x8 v1 = ((const u16x8*)(x + (size_t)j1*XP))[lane];
                u16x8 v2 = ((const u16x8*)(x + (size_t)j2*XP))[lane];
                u16x8 v3 = ((const u16x8*)(x + (size_t)j3*XP))[lane];
                c0 += q0*us2f(v0[0])+q1*us2f(v1[0])+q2*us2f(v2[0])+q3*us2f(v3[0]);
                c1 += q0*us2f(v0[1])+q1*us2f(v1[1])+q2*us2f(v2[1])+q3*us2f(v3[1]);
                c2 += q0*us2f(v0[2])+q1*us2f(v1[2])+q2*us2f(v2[2])+q3*us2f(v3[2]);
                c3 += q0*us2f(v0[3])+q1*us2f(v1[3])+q2*us2f(v2[3])+q3*us2f(v3[3]);
                c4 += q0*us2f(v0[4])+q1*us2f(v1[4])+q2*us2f(v2[4])+q3*us2f(v3[4]);
                c5 += q0*us2f(v0[5])+q1*us2f(v1[5])+q2*us2f(v2[5])+q3*us2f(v3[5]);
                c6 += q0*us2f(v0[6])+q1*us2f(v1[6])+q2*us2f(v2[6])+q3*us2f(v3[6]);
                c7 += q0*us2f(v0[7])+q1*us2f(v1[7])+q2*us2f(v2[7])+q3*us2f(v3[7]);
            }
        }
        for(; it < cnt; it++){
            int j0 = rdl_i(jl, it);
            float q0 = rdl_f(al, it);
            if(act){
                u16x8 v0 = ((const u16x8*)(x + (size_t)j0*XP))[lane];
                c0 += q0*us2f(v0[0]); c1 += q0*us2f(v0[1]); c2 += q0*us2f(v0[2]); c3 += q0*us2f(v0[3]);
                c4 += q0*us2f(v0[4]); c5 += q0*us2f(v0[5]); c6 += q0*us2f(v0[6]); c7 += q0*us2f(v0[7]);
            }
        }
    } else if(cnt > 64){
        float mx = -1e30f;
        for(int it=s0; it<s1; it++){
            float lg = p + ajv[clampi(adjj[it], NN)];
            lg = lg > 0 ? lg : 0.01f*lg;
            mx = fmaxf(mx, lg);
        }
        float ssum = 0.f;
        for(int it=s0; it<s1; it++){
            float lg = p + ajv[clampi(adjj[it], NN)];
            lg = lg > 0 ? lg : 0.01f*lg;
            ssum += __expf(lg - mx);
        }
        float rinv = __builtin_amdgcn_rcpf(ssum);
        for(int it=s0; it<s1; it++){
            int j = clampi(adjj[it], NN);
            float lg = p + ajv[j];
            lg = lg > 0 ? lg : 0.01f*lg;
            float aw = __expf(lg - mx)*rinv;
            if(act){
                u16x8 v0 = ((const u16x8*)(x + (size_t)j*XP))[lane];
                c0 += aw*us2f(v0[0]); c1 += aw*us2f(v0[1]); c2 += aw*us2f(v0[2]); c3 += aw*us2f(v0[3]);
                c4 += aw*us2f(v0[4]); c5 += aw*us2f(v0[5]); c6 += aw*us2f(v0[6]); c7 += aw*us2f(v0[7]);
            }
        }
    }
    float part = 0.f;
    if(act){
        const float4* f5 = (const float4*)(apad + 5*XP);
        const float4* f6 = (const float4*)(apad + 6*XP);
        float4 u0 = f5[2*lane], u1 = f5[2*lane+1];
        float4 g0 = f6[2*lane], g1 = f6[2*lane+1];
        part = xv[0]*u0.x + xv[1]*u0.y + xv[2]*u0.z + xv[3]*u0.w
             + xv[4]*u1.x + xv[5]*u1.y + xv[6]*u1.z + xv[7]*u1.w
             + fmaxf(c0,0.f)*g0.x + fmaxf(c1,0.f)*g0.y + fmaxf(c2,0.f)*g0.z + fmaxf(c3,0.f)*g0.w
             + fmaxf(c4,0.f)*g1.x + fmaxf(c5,0.f)*g1.y + fmaxf(c6,0.f)*g1.z + fmaxf(c7,0.f)*g1.w;
    }
    part = dpp_sum(part);
    if(lane == 0) out[n] = part + fcb[0];
}

extern "C" void kernel_launch(void* const* d_in, const int* in_sizes, int n_in,
                              void* d_out, int out_size, void* d_ws, size_t ws_size,
                              hipStream_t stream){
    const float* x_in = (const float*)d_in[0];
    const int*  ht   = (const int*)d_in[1];
    const int*  rel  = (const int*)d_in[2];
    const int*  ji   = (const int*)d_in[3];
    const float* hw1w=(const float*)d_in[5];  const float* hw1b=(const float*)d_in[6];
    const float* hw2w=(const float*)d_in[7];  const float* hw2b=(const float*)d_in[8];
    const float* tc1w=(const float*)d_in[9];  const float* tc1b=(const float*)d_in[10];
    const float* sr1w=(const float*)d_in[11]; const float* sr1b=(const float*)d_in[12];
    const float* wrw =(const float*)d_in[15]; const float* wrb =(const float*)d_in[16];
    const float* wr1w=(const float*)d_in[17]; const float* wr1b=(const float*)d_in[18];
    const float* wr2w=(const float*)d_in[19]; const float* wr2b=(const float*)d_in[20];
    const float* ahw =(const float*)d_in[21]; const float* ah1w=(const float*)d_in[22];
    const float* atw =(const float*)d_in[23];
    const float* ar1 =(const float*)d_in[24]; const float* ar2 =(const float*)d_in[25];
    const float* ar3 =(const float*)d_in[26];
    const float* aiw =(const float*)d_in[27]; const float* ajw =(const float*)d_in[28];
    const float* fcw =(const float*)d_in[29]; const float* fcb =(const float*)d_in[30];
    float* out = (float*)d_out;

    char* w = (char*)d_ws;
    auto alloc = [&](size_t bytes)->char*{ char* p = w; w += (bytes + 255)/256*256; return p; };
    bf16* xF = (bf16*)alloc((size_t)NN128*XP*2);    // 32 MB padded
    bf16* B  = (bf16*)alloc((size_t)NN128*XP*2);    // 32 MB padded; CSR tmp -> gcn/x1 -> rel tables
    char* Bc = (char*)B;
    int2* tmp_all = (int2*)(Bc);                      // 4 MB
    int2* tmp_h   = (int2*)(Bc + 4u*1024*1024);       // 2 MB
    int2* tmp_t   = (int2*)(Bc + 8u*1024*1024);       // 2 MB
    int2* tmp_r   = (int2*)(Bc + 12u*1024*1024);      // 2 MB
    bf16*  sbuf   = (bf16*)(Bc);                      // 10.01 MB (after CSR phase)
    float* RFpart = (float*)(Bc + 10u*1024*1024 + 512u*1024);  // 7.68 MB (RCH=32)
    bf16*  ER     = (bf16*)(Bc + 18u*1024*1024 + 512u*1024);   // 576 KB (bf16 padded rows)
    float* cvec   = (float*)(Bc + 19u*1024*1024 + 256u*1024);
    float* ajv    = (float*)(Bc + 19u*1024*1024 + 512u*1024);
    short* Wt1 = (short*)alloc((size_t)320*320*2);
    short* Wt2 = (short*)alloc((size_t)320*320*2);
    short* Wtc = (short*)alloc((size_t)128*320*2);
    float* apad = (float*)alloc((size_t)7*XP*4);
    float* dinv = (float*)alloc((size_t)NN*4);
    int* off_all=(int*)alloc((NN+1)*4);
    int* adj_all=(int*)alloc((size_t)NEA*4);
    int* off_h  =(int*)alloc((NN+1)*4);
    int* adj_h  =(int*)alloc((size_t)NE*4);
    int* off_t  =(int*)alloc((NN+1)*4);
    int* adj_t  =(int*)alloc((size_t)NE*4);
    int* off_r  =(int*)alloc((NR+1)*4);
    int* adj_r  =(int*)alloc((size_t)NE*4);
    int* bcnt   =(int*)alloc(512*4);
    int* gbase  =(int*)alloc(4*129*4);
    int* gcur   =(int*)alloc(4*128*4);

    hipMemsetAsync(bcnt, 0, 512*4, stream);
    k_prepc<<<dim3(PREP_NB + 4*BCNT_NB), dim3(256), 0, stream>>>(x_in, (ushort*)xF, hw1w, hw2w, tc1w,
                                                          Wt1, Wt2, Wtc,
                                                          ahw, atw, ah1w, ajw, aiw, fcw,
                                                          apad, bcnt, ji, ht, rel);
    k_bscan<<<dim3(1), dim3(512), 0, stream>>>(bcnt, gbase, gcur);
    k_bin<<<dim3((NEA+2047)/2048, 4), dim3(256), 0, stream>>>(ji, ht, rel, gcur,
                                                              tmp_all, tmp_h, tmp_t, tmp_r);
    k_place<<<dim3(NBN, 4), dim3(256), 0, stream>>>(gbase, tmp_all, tmp_h, tmp_t, tmp_r,
                                                    off_all, off_h, off_t, off_r,
                                                    adj_all, adj_h, adj_t, adj_r, dinv);

    // highway 1: B = gcn(xF); B = sig(xF@W1+b)*B + (1-sig)*xF
    k_gcn<<<dim3(NB4), dim3(256), 0, stream>>>(xF, B, off_all, adj_all, dinv);
    k_gemm_mfma<1><<<dim3((NN128/64)*5), dim3(256), 0, stream>>>(xF, Wt1, hw1b, B, xF, NN, XP, EHD, XP, 5);
    // highway 2
    k_gcn<<<dim3(NB4), dim3(256), 0, stream>>>(B, xF, off_all, adj_all, dinv);
    k_gemm_mfma<1><<<dim3((NN128/64)*5), dim3(256), 0, stream>>>(B, Wt2, hw2b, xF, B, NN, XP, EHD, XP, 5);
    // rel tables
    k_gemm_mfma<0><<<dim3((NN128/64)*2), dim3(256), 0, stream>>>(xF, Wtc, tc1b, sbuf, xF, NN, XP, THD, THD, 2);
    k_relsum2<<<dim3(NR, RCH), dim3(128), 0, stream>>>(sbuf, ht, off_r, adj_r, RFpart);
    k_reler<<<dim3(NR, 3), dim3(256), 0, stream>>>(RFpart, off_r, sr1w, sr1b,
                                                   wrw, wrb, wr1w, wr1b, wr2w, wr2b,
                                                   ar1, ar2, ar3, ER, cvec);
    // fused three r2e rounds + ajv
    k_r2e3<<<dim3(NB4), dim3(256), 0, stream>>>(xF, off_h, adj_h, off_t, adj_t, ER, cvec,
                                                apad, ajv);
    // final GAT + fc
    k_final<<<dim3(NB4), dim3(256), 0, stream>>>(xF, ajv, off_all, adj_all, apad, fcb, out);
}